// Round 18
// baseline (295.887 us; speedup 1.0000x reference)
//
#include <hip/hip_runtime.h>
#include <hip/hip_fp16.h>
#include <cstdint>
#include <cstddef>

#define Bb 32
#define Ss 2048
#define Ee 1024
#define Qq 1024
#define Aa 512

typedef _Float16 half8 __attribute__((ext_vector_type(8)));
typedef _Float16 half4 __attribute__((ext_vector_type(4)));
typedef __fp16 fp16x2 __attribute__((ext_vector_type(2)));
typedef float f32x4 __attribute__((ext_vector_type(4)));

// ---- workspace byte offsets ----
#define WS_PROJQ 0u          // 32*512 f32      = 65536 B
#define WS_MPART 65536u      // 32*16 f32       = 2048 B
#define WS_LPART 67584u      // 32*16 f32       = 2048 B
#define WS_CTXP  69632u      // 32*16*512 f32   = 1048576 B
#define WS_WWS   1118208u    // 1024*512 f16    = 1048576 B
#define WS_CNT   2166784u    // 32 int          = 128 B

__device__ __forceinline__ float fast_tanh(float x) {
  float e = __expf(2.0f * x);
  return 1.0f - __fdividef(2.0f, e + 1.0f);
}

// packed f32x2 -> f16x2 convert
__device__ __forceinline__ half4 cvt4(float4 x) {
  fp16x2 lo = __builtin_amdgcn_cvt_pkrtz(x.x, x.y);
  fp16x2 hi = __builtin_amdgcn_cvt_pkrtz(x.z, x.w);
  half4 r;
  r[0] = (_Float16)lo[0]; r[1] = (_Float16)lo[1];
  r[2] = (_Float16)hi[0]; r[3] = (_Float16)hi[1];
  return r;
}

// ---- merged prep: blocks 0..255 convert W_in -> fp16 tiled; blocks 256..511 proj_q.
// Also zeros the per-batch combine counters each call (determinism).
__global__ void k_prep(const float* __restrict__ win, _Float16* __restrict__ wws,
                       const float* __restrict__ query, const float* __restrict__ wq,
                       float* __restrict__ projq, int* __restrict__ cnt) {
  if (blockIdx.x == 0 && threadIdx.x < 32) cnt[threadIdx.x] = 0;
  if (blockIdx.x < 256) {
    int gid = blockIdx.x * 256 + threadIdx.x;
    int a  = gid & 511;
    int ks = (gid >> 9) & 3;
    int kt = gid >> 11;
    int k0 = kt * 32 + ks * 8;
    half8 v;
    #pragma unroll
    for (int j = 0; j < 8; ++j) v[j] = (_Float16)win[(size_t)(k0 + j) * Aa + a];
    *(half8*)(wws + ((size_t)kt * 16384 + (size_t)ks * 4096 + (size_t)a * 8)) = v;
  } else {
    __shared__ float red[256];
    int pb = blockIdx.x - 256;       // 0..255
    int b  = pb >> 3;
    int ax = pb & 7;
    int al = threadIdx.x & 63;
    int eq = threadIdx.x >> 6;
    int a  = ax * 64 + al;
    const float* q = query + (size_t)b * Qq;
    float s = 0.f;
    int e0 = eq * 256;
    #pragma unroll 4
    for (int e = e0; e < e0 + 256; ++e)
      s += q[e] * wq[(size_t)e * Aa + a];
    red[threadIdx.x] = s;
    __syncthreads();
    if (eq == 0)
      projq[(size_t)b * Aa + a] = red[al] + red[al + 64] + red[al + 128] + red[al + 192];
  }
}

// ---- main: R17 kernel (best-known) + fused last-block combine (replaces k_comb).
__global__ __launch_bounds__(1024, 4)
void k_main(const float* __restrict__ inp, const _Float16* __restrict__ wws,
            const float* __restrict__ projq, const float* __restrict__ watt,
            float* __restrict__ mpart, float* __restrict__ lpart,
            float* __restrict__ ctxp, int* __restrict__ cnt,
            float* __restrict__ out)
{
  __shared__ __align__(16) _Float16 Alds[2][4 * 128 * 8];   // [p][ks][row128][8] 2x8KB
  __shared__ __align__(16) _Float16 Blds[2][4 * 512 * 8];   // [p][ks][a][8]      2x32KB
  __shared__ float pq_s[512];
  __shared__ float wa_s[512];
  __shared__ float sc8[128][8];
  __shared__ float pbuf[128];
  __shared__ float red2[8];
  __shared__ float ctx2[2][512];
  __shared__ int isLast;

  const int tid = threadIdx.x;
  const int l   = tid & 63;
  const int w   = tid >> 6;        // wave 0..15
  const int lr  = l & 15;
  const int kb  = l >> 4;          // k-slot 0..3
  const int wr  = w >> 3;          // m-half 0..1 (rows wr*64 .. +63)
  const int wc  = w & 7;           // n-slice 0..7 (cols wc*64 .. +63)
  const int b   = blockIdx.y;
  const int ch  = blockIdx.x;      // s-chunk of 128 rows, 0..15

  if (tid < 512) {
    pq_s[tid] = projq[(size_t)b * Aa + tid];
    wa_s[tid] = watt[tid];
  }

  // A staging: thread t -> row = t>>3 (0..127), kq = t&7 (float4 group)
  const int arow = tid >> 3;
  const int kq   = tid & 7;
  const float* asrc = inp + ((size_t)(b * Ss + ch * 128 + arow)) * Ee + kq * 4;
  const int awoff = ((kq >> 1) * 128 + arow) * 8 + (kq & 1) * 4;   // f16 elem offset

  // B staging: 2 x 16B per thread, linear (tid*16 + i*16384 covers 32KB/kt)
  const char* bsrc0 = (const char*)wws + (size_t)tid * 16;

  f32x4 acc[4][4];
  #pragma unroll
  for (int m = 0; m < 4; ++m)
    #pragma unroll
    for (int n = 0; n < 4; ++n) acc[m][n] = (f32x4){0.f, 0.f, 0.f, 0.f};

  // ---- prologue: stage kt=0 into buf 0; preload A(1)
  {
    float4 x = *(const float4*)(asrc);              // A(0)
    *(half4*)(Alds[0] + awoff) = cvt4(x);
    #pragma unroll
    for (int i = 0; i < 2; ++i)
      __builtin_amdgcn_global_load_lds(
        (const __attribute__((address_space(1))) void*)(bsrc0 + i * 16384),
        (__attribute__((address_space(3))) void*)((char*)Blds[0] + tid * 16 + i * 16384),
        16, 0, 0);
  }
  float4 areg = *(const float4*)(asrc + 32);        // A(1)
  __syncthreads();

  int p = 0;
  for (int kt = 0; kt < 32; ++kt) {
    // 1) issue B(kt+1) gloads into buf p^1 (whole MFMA phase to land)
    if (kt < 31) {
      const char* bs = bsrc0 + (size_t)(kt + 1) * 32768;
      #pragma unroll
      for (int i = 0; i < 2; ++i)
        __builtin_amdgcn_global_load_lds(
          (const __attribute__((address_space(1))) void*)(bs + i * 16384),
          (__attribute__((address_space(3))) void*)((char*)Blds[p ^ 1] + tid * 16 + i * 16384),
          16, 0, 0);
    }
    // 2) A(kt+2) into regs (consumed NEXT iteration)
    const int ktn2 = (kt < 30) ? kt + 2 : 31;
    float4 anext = *(const float4*)(asrc + (size_t)ktn2 * 32);

    // 3) fragments(kt) from LDS[p]: 4 A + 4 B reads
    half8 af0 = *(const half8*)(Alds[p] + (kb * 128 + wr * 64 +      lr) * 8);
    half8 af1 = *(const half8*)(Alds[p] + (kb * 128 + wr * 64 + 16 + lr) * 8);
    half8 af2 = *(const half8*)(Alds[p] + (kb * 128 + wr * 64 + 32 + lr) * 8);
    half8 af3 = *(const half8*)(Alds[p] + (kb * 128 + wr * 64 + 48 + lr) * 8);
    const _Float16* Bp = Blds[p] + (kb * 512 + wc * 64 + lr) * 8;
    half8 bf0 = *(const half8*)(Bp);
    half8 bf1 = *(const half8*)(Bp + 16 * 8);
    half8 bf2 = *(const half8*)(Bp + 32 * 8);
    half8 bf3 = *(const half8*)(Bp + 48 * 8);

    acc[0][0] = __builtin_amdgcn_mfma_f32_16x16x32_f16(af0, bf0, acc[0][0], 0, 0, 0);
    acc[0][1] = __builtin_amdgcn_mfma_f32_16x16x32_f16(af0, bf1, acc[0][1], 0, 0, 0);
    acc[0][2] = __builtin_amdgcn_mfma_f32_16x16x32_f16(af0, bf2, acc[0][2], 0, 0, 0);
    acc[0][3] = __builtin_amdgcn_mfma_f32_16x16x32_f16(af0, bf3, acc[0][3], 0, 0, 0);
    acc[1][0] = __builtin_amdgcn_mfma_f32_16x16x32_f16(af1, bf0, acc[1][0], 0, 0, 0);
    acc[1][1] = __builtin_amdgcn_mfma_f32_16x16x32_f16(af1, bf1, acc[1][1], 0, 0, 0);
    acc[1][2] = __builtin_amdgcn_mfma_f32_16x16x32_f16(af1, bf2, acc[1][2], 0, 0, 0);
    acc[1][3] = __builtin_amdgcn_mfma_f32_16x16x32_f16(af1, bf3, acc[1][3], 0, 0, 0);
    acc[2][0] = __builtin_amdgcn_mfma_f32_16x16x32_f16(af2, bf0, acc[2][0], 0, 0, 0);
    acc[2][1] = __builtin_amdgcn_mfma_f32_16x16x32_f16(af2, bf1, acc[2][1], 0, 0, 0);
    acc[2][2] = __builtin_amdgcn_mfma_f32_16x16x32_f16(af2, bf2, acc[2][2], 0, 0, 0);
    acc[2][3] = __builtin_amdgcn_mfma_f32_16x16x32_f16(af2, bf3, acc[2][3], 0, 0, 0);
    acc[3][0] = __builtin_amdgcn_mfma_f32_16x16x32_f16(af3, bf0, acc[3][0], 0, 0, 0);
    acc[3][1] = __builtin_amdgcn_mfma_f32_16x16x32_f16(af3, bf1, acc[3][1], 0, 0, 0);
    acc[3][2] = __builtin_amdgcn_mfma_f32_16x16x32_f16(af3, bf2, acc[3][2], 0, 0, 0);
    acc[3][3] = __builtin_amdgcn_mfma_f32_16x16x32_f16(af3, bf3, acc[3][3], 0, 0, 0);

    // 4) write A(kt+1) (loaded LAST iteration) into buf p^1
    if (kt < 31) {
      *(half4*)(Alds[p ^ 1] + awoff) = cvt4(areg);
    }
    __syncthreads();
    p ^= 1;
    areg = anext;
  }

  // ---------------- epilogue ----------------
  // C/D: col = lane&15, frag row = kb*4 + j
  // global row = wr*64 + m*16 + kb*4 + j ; global col = wc*64 + n*16 + lr
  float sp[4][4];
  #pragma unroll
  for (int m = 0; m < 4; ++m)
    #pragma unroll
    for (int j = 0; j < 4; ++j) sp[m][j] = 0.f;

  #pragma unroll
  for (int n = 0; n < 4; ++n) {
    int col = wc * 64 + n * 16 + lr;
    float wan = wa_s[col], pqn = pq_s[col];
    #pragma unroll
    for (int m = 0; m < 4; ++m)
      #pragma unroll
      for (int j = 0; j < 4; ++j)
        sp[m][j] += fast_tanh(acc[m][n][j] + pqn) * wan;
  }
  #pragma unroll
  for (int m = 0; m < 4; ++m)
    #pragma unroll
    for (int j = 0; j < 4; ++j) {
      float v = sp[m][j];
      v += __shfl_xor(v, 1);
      v += __shfl_xor(v, 2);
      v += __shfl_xor(v, 4);
      v += __shfl_xor(v, 8);
      sp[m][j] = v;                    // reduced over this wave's 16-col group
    }
  if (lr == 0) {
    #pragma unroll
    for (int m = 0; m < 4; ++m)
      #pragma unroll
      for (int j = 0; j < 4; ++j)
        sc8[wr * 64 + m * 16 + kb * 4 + j][wc] = sp[m][j];
  }
  __syncthreads();

  // row scores (128 rows on waves 0-1), two-level max/sum
  const int pi = b * 16 + ch;
  float s = 0.f, pe = 0.f;
  if (tid < 128) {
    s = sc8[tid][0] + sc8[tid][1] + sc8[tid][2] + sc8[tid][3]
      + sc8[tid][4] + sc8[tid][5] + sc8[tid][6] + sc8[tid][7];
    float mx = s;
    #pragma unroll
    for (int off = 1; off < 64; off <<= 1) mx = fmaxf(mx, __shfl_xor(mx, off));
    if (l == 0) red2[w] = mx;
  }
  __syncthreads();
  float Mx = fmaxf(red2[0], red2[1]);
  if (tid < 128) {
    pe = __expf(s - Mx);
    pbuf[tid] = pe;
    float ls = pe;
    #pragma unroll
    for (int off = 1; off < 64; off <<= 1) ls += __shfl_xor(ls, off);
    if (l == 0) red2[4 + w] = ls;
  }
  __syncthreads();
  if (tid == 0) { mpart[pi] = Mx; lpart[pi] = red2[4] + red2[5]; }

  // ctx partial: cv[n] = sum over this wave's 64 rows of p[row]*proj[row][col]
  float cv[4];
  #pragma unroll
  for (int n = 0; n < 4; ++n) cv[n] = 0.f;
  #pragma unroll
  for (int m = 0; m < 4; ++m)
    #pragma unroll
    for (int j = 0; j < 4; ++j) {
      float pw = pbuf[wr * 64 + m * 16 + kb * 4 + j];
      #pragma unroll
      for (int n = 0; n < 4; ++n) cv[n] += pw * acc[m][n][j];
    }
  #pragma unroll
  for (int n = 0; n < 4; ++n) {
    float v = cv[n];
    v += __shfl_xor(v, 16);
    v += __shfl_xor(v, 32);
    cv[n] = v;                         // summed over kb-groups -> all 64 rows
  }
  if (l < 16) {
    #pragma unroll
    for (int n = 0; n < 4; ++n) ctx2[wr][wc * 64 + n * 16 + l] = cv[n];
  }
  __syncthreads();

  if (tid < 512)
    ctxp[(size_t)pi * 512 + tid] = ctx2[0][tid] + ctx2[1][tid];

  // ---------------- fused combine: last block of batch b does k_comb's work ----
  __threadfence();                       // release partials (device scope)
  if (tid == 0) {
    int v = atomicAdd(&cnt[b], 1);       // device-scope by default (G12)
    isLast = (v == 15);
  }
  __syncthreads();
  if (isLast) {
    __threadfence();                     // acquire others' partials
    if (tid < 512) {
      float Mg = -1e30f;
      #pragma unroll
      for (int i = 0; i < 16; ++i) Mg = fmaxf(Mg, mpart[b * 16 + i]);
      float den = 0.f, sm = 0.f;
      #pragma unroll
      for (int i = 0; i < 16; ++i) {
        float e = __expf(mpart[b * 16 + i] - Mg);
        den += lpart[b * 16 + i] * e;
        sm  += ctxp[((size_t)(b * 16 + i)) * 512 + tid] * e;
      }
      out[(size_t)b * 512 + tid] = sm / den;
    }
  }
}

extern "C" void kernel_launch(void* const* d_in, const int* in_sizes, int n_in,
                              void* d_out, int out_size, void* d_ws, size_t ws_size,
                              hipStream_t stream) {
  const float* inputs = (const float*)d_in[0];
  const float* query  = (const float*)d_in[1];
  const float* W_in   = (const float*)d_in[2];
  const float* W_q    = (const float*)d_in[3];
  const float* w_att  = (const float*)d_in[4];
  float* out = (float*)d_out;

  char* ws = (char*)d_ws;
  float*    projq = (float*)(ws + WS_PROJQ);
  float*    mpart = (float*)(ws + WS_MPART);
  float*    lpart = (float*)(ws + WS_LPART);
  float*    ctxp  = (float*)(ws + WS_CTXP);
  _Float16* wws   = (_Float16*)(ws + WS_WWS);
  int*      cnt   = (int*)(ws + WS_CNT);

  k_prep<<<512, 256, 0, stream>>>(W_in, wws, query, W_q, projq, cnt);
  k_main<<<dim3(16, 32), 1024, 0, stream>>>(inputs, wws, projq, w_att,
                                            mpart, lpart, ctxp, cnt, out);
}

// Round 19
// 133.025 us; speedup vs baseline: 2.2243x; 2.2243x over previous
//
#include <hip/hip_runtime.h>
#include <hip/hip_fp16.h>
#include <cstdint>
#include <cstddef>

#define Bb 32
#define Ss 2048
#define Ee 1024
#define Qq 1024
#define Aa 512

typedef _Float16 half8 __attribute__((ext_vector_type(8)));
typedef _Float16 half4 __attribute__((ext_vector_type(4)));
typedef __fp16 fp16x2 __attribute__((ext_vector_type(2)));
typedef float f32x4 __attribute__((ext_vector_type(4)));

// ---- workspace byte offsets ----
#define WS_PROJQ 0u          // 32*512 f32      = 65536 B
#define WS_MPART 65536u      // 32*16 f32       = 2048 B
#define WS_LPART 67584u      // 32*16 f32       = 2048 B
#define WS_CTXP  69632u      // 32*16*512 f32   = 1048576 B
#define WS_WWS   1118208u    // 1024*512 f16    = 1048576 B

__device__ __forceinline__ float fast_tanh(float x) {
  float e = __expf(2.0f * x);
  return 1.0f - __fdividef(2.0f, e + 1.0f);
}

// packed f32x2 -> f16x2 convert
__device__ __forceinline__ half4 cvt4(float4 x) {
  fp16x2 lo = __builtin_amdgcn_cvt_pkrtz(x.x, x.y);
  fp16x2 hi = __builtin_amdgcn_cvt_pkrtz(x.z, x.w);
  half4 r;
  r[0] = (_Float16)lo[0]; r[1] = (_Float16)lo[1];
  r[2] = (_Float16)hi[0]; r[3] = (_Float16)hi[1];
  return r;
}

// ---- merged prep: blocks 0..255 convert W_in -> fp16 tiled; blocks 256..511 proj_q
__global__ void k_prep(const float* __restrict__ win, _Float16* __restrict__ wws,
                       const float* __restrict__ query, const float* __restrict__ wq,
                       float* __restrict__ projq) {
  if (blockIdx.x < 256) {
    int gid = blockIdx.x * 256 + threadIdx.x;
    int a  = gid & 511;
    int ks = (gid >> 9) & 3;
    int kt = gid >> 11;
    int k0 = kt * 32 + ks * 8;
    half8 v;
    #pragma unroll
    for (int j = 0; j < 8; ++j) v[j] = (_Float16)win[(size_t)(k0 + j) * Aa + a];
    *(half8*)(wws + ((size_t)kt * 16384 + (size_t)ks * 4096 + (size_t)a * 8)) = v;
  } else {
    __shared__ float red[256];
    int pb = blockIdx.x - 256;       // 0..255
    int b  = pb >> 3;
    int ax = pb & 7;
    int al = threadIdx.x & 63;
    int eq = threadIdx.x >> 6;
    int a  = ax * 64 + al;
    const float* q = query + (size_t)b * Qq;
    float s = 0.f;
    int e0 = eq * 256;
    #pragma unroll 4
    for (int e = e0; e < e0 + 256; ++e)
      s += q[e] * wq[(size_t)e * Aa + a];
    red[threadIdx.x] = s;
    __syncthreads();
    if (eq == 0)
      projq[(size_t)b * Aa + a] = red[al] + red[al + 64] + red[al + 128] + red[al + 192];
  }
}

// ---- main: BM=128 x BN=512, BK=32, 1024 thr, 16 waves as 2wr x 8wc.
// Wave owns 64 rows x 64 cols -> 4 A-frag + 4 B-frag ds_reads per kt.
__global__ __launch_bounds__(1024, 4)
void k_main(const float* __restrict__ inp, const _Float16* __restrict__ wws,
            const float* __restrict__ projq, const float* __restrict__ watt,
            float* __restrict__ mpart, float* __restrict__ lpart,
            float* __restrict__ ctxp)
{
  __shared__ __align__(16) _Float16 Alds[2][4 * 128 * 8];   // [p][ks][row128][8] 2x8KB
  __shared__ __align__(16) _Float16 Blds[2][4 * 512 * 8];   // [p][ks][a][8]      2x32KB
  __shared__ float pq_s[512];
  __shared__ float wa_s[512];
  __shared__ float sc8[128][8];
  __shared__ float pbuf[128];
  __shared__ float red2[8];
  __shared__ float ctx2[2][512];

  const int tid = threadIdx.x;
  const int l   = tid & 63;
  const int w   = tid >> 6;        // wave 0..15
  const int lr  = l & 15;
  const int kb  = l >> 4;          // k-slot 0..3
  const int wr  = w >> 3;          // m-half 0..1 (rows wr*64 .. +63)
  const int wc  = w & 7;           // n-slice 0..7 (cols wc*64 .. +63)
  const int b   = blockIdx.y;
  const int ch  = blockIdx.x;      // s-chunk of 128 rows, 0..15

  if (tid < 512) {
    pq_s[tid] = projq[(size_t)b * Aa + tid];
    wa_s[tid] = watt[tid];
  }

  // A staging: thread t -> row = t>>3 (0..127), kq = t&7 (float4 group)
  const int arow = tid >> 3;
  const int kq   = tid & 7;
  const float* asrc = inp + ((size_t)(b * Ss + ch * 128 + arow)) * Ee + kq * 4;
  const int awoff = ((kq >> 1) * 128 + arow) * 8 + (kq & 1) * 4;   // f16 elem offset

  // B staging: 2 x 16B per thread, linear (tid*16 + i*16384 covers 32KB/kt)
  const char* bsrc0 = (const char*)wws + (size_t)tid * 16;

  f32x4 acc[4][4];
  #pragma unroll
  for (int m = 0; m < 4; ++m)
    #pragma unroll
    for (int n = 0; n < 4; ++n) acc[m][n] = (f32x4){0.f, 0.f, 0.f, 0.f};

  // ---- prologue: stage kt=0 into buf 0; preload A(1)
  {
    float4 x = *(const float4*)(asrc);              // A(0)
    *(half4*)(Alds[0] + awoff) = cvt4(x);
    #pragma unroll
    for (int i = 0; i < 2; ++i)
      __builtin_amdgcn_global_load_lds(
        (const __attribute__((address_space(1))) void*)(bsrc0 + i * 16384),
        (__attribute__((address_space(3))) void*)((char*)Blds[0] + tid * 16 + i * 16384),
        16, 0, 0);
  }
  float4 areg = *(const float4*)(asrc + 32);        // A(1)
  __syncthreads();

  int p = 0;
  for (int kt = 0; kt < 32; ++kt) {
    // 1) issue B(kt+1) gloads into buf p^1 (whole MFMA phase to land)
    if (kt < 31) {
      const char* bs = bsrc0 + (size_t)(kt + 1) * 32768;
      #pragma unroll
      for (int i = 0; i < 2; ++i)
        __builtin_amdgcn_global_load_lds(
          (const __attribute__((address_space(1))) void*)(bs + i * 16384),
          (__attribute__((address_space(3))) void*)((char*)Blds[p ^ 1] + tid * 16 + i * 16384),
          16, 0, 0);
    }
    // 2) A(kt+2) into regs (consumed NEXT iteration)
    const int ktn2 = (kt < 30) ? kt + 2 : 31;
    float4 anext = *(const float4*)(asrc + (size_t)ktn2 * 32);

    // 3) fragments(kt) from LDS[p]: 4 A + 4 B reads
    half8 af0 = *(const half8*)(Alds[p] + (kb * 128 + wr * 64 +      lr) * 8);
    half8 af1 = *(const half8*)(Alds[p] + (kb * 128 + wr * 64 + 16 + lr) * 8);
    half8 af2 = *(const half8*)(Alds[p] + (kb * 128 + wr * 64 + 32 + lr) * 8);
    half8 af3 = *(const half8*)(Alds[p] + (kb * 128 + wr * 64 + 48 + lr) * 8);
    const _Float16* Bp = Blds[p] + (kb * 512 + wc * 64 + lr) * 8;
    half8 bf0 = *(const half8*)(Bp);
    half8 bf1 = *(const half8*)(Bp + 16 * 8);
    half8 bf2 = *(const half8*)(Bp + 32 * 8);
    half8 bf3 = *(const half8*)(Bp + 48 * 8);

    acc[0][0] = __builtin_amdgcn_mfma_f32_16x16x32_f16(af0, bf0, acc[0][0], 0, 0, 0);
    acc[0][1] = __builtin_amdgcn_mfma_f32_16x16x32_f16(af0, bf1, acc[0][1], 0, 0, 0);
    acc[0][2] = __builtin_amdgcn_mfma_f32_16x16x32_f16(af0, bf2, acc[0][2], 0, 0, 0);
    acc[0][3] = __builtin_amdgcn_mfma_f32_16x16x32_f16(af0, bf3, acc[0][3], 0, 0, 0);
    acc[1][0] = __builtin_amdgcn_mfma_f32_16x16x32_f16(af1, bf0, acc[1][0], 0, 0, 0);
    acc[1][1] = __builtin_amdgcn_mfma_f32_16x16x32_f16(af1, bf1, acc[1][1], 0, 0, 0);
    acc[1][2] = __builtin_amdgcn_mfma_f32_16x16x32_f16(af1, bf2, acc[1][2], 0, 0, 0);
    acc[1][3] = __builtin_amdgcn_mfma_f32_16x16x32_f16(af1, bf3, acc[1][3], 0, 0, 0);
    acc[2][0] = __builtin_amdgcn_mfma_f32_16x16x32_f16(af2, bf0, acc[2][0], 0, 0, 0);
    acc[2][1] = __builtin_amdgcn_mfma_f32_16x16x32_f16(af2, bf1, acc[2][1], 0, 0, 0);
    acc[2][2] = __builtin_amdgcn_mfma_f32_16x16x32_f16(af2, bf2, acc[2][2], 0, 0, 0);
    acc[2][3] = __builtin_amdgcn_mfma_f32_16x16x32_f16(af2, bf3, acc[2][3], 0, 0, 0);
    acc[3][0] = __builtin_amdgcn_mfma_f32_16x16x32_f16(af3, bf0, acc[3][0], 0, 0, 0);
    acc[3][1] = __builtin_amdgcn_mfma_f32_16x16x32_f16(af3, bf1, acc[3][1], 0, 0, 0);
    acc[3][2] = __builtin_amdgcn_mfma_f32_16x16x32_f16(af3, bf2, acc[3][2], 0, 0, 0);
    acc[3][3] = __builtin_amdgcn_mfma_f32_16x16x32_f16(af3, bf3, acc[3][3], 0, 0, 0);

    // 4) write A(kt+1) (loaded LAST iteration) into buf p^1
    if (kt < 31) {
      *(half4*)(Alds[p ^ 1] + awoff) = cvt4(areg);
    }
    __syncthreads();
    p ^= 1;
    areg = anext;
  }

  // ---------------- epilogue ----------------
  // C/D: col = lane&15, frag row = kb*4 + j
  // global row = wr*64 + m*16 + kb*4 + j ; global col = wc*64 + n*16 + lr
  float sp[4][4];
  #pragma unroll
  for (int m = 0; m < 4; ++m)
    #pragma unroll
    for (int j = 0; j < 4; ++j) sp[m][j] = 0.f;

  #pragma unroll
  for (int n = 0; n < 4; ++n) {
    int col = wc * 64 + n * 16 + lr;
    float wan = wa_s[col], pqn = pq_s[col];
    #pragma unroll
    for (int m = 0; m < 4; ++m)
      #pragma unroll
      for (int j = 0; j < 4; ++j)
        sp[m][j] += fast_tanh(acc[m][n][j] + pqn) * wan;
  }
  #pragma unroll
  for (int m = 0; m < 4; ++m)
    #pragma unroll
    for (int j = 0; j < 4; ++j) {
      float v = sp[m][j];
      v += __shfl_xor(v, 1);
      v += __shfl_xor(v, 2);
      v += __shfl_xor(v, 4);
      v += __shfl_xor(v, 8);
      sp[m][j] = v;                    // reduced over this wave's 16-col group
    }
  if (lr == 0) {
    #pragma unroll
    for (int m = 0; m < 4; ++m)
      #pragma unroll
      for (int j = 0; j < 4; ++j)
        sc8[wr * 64 + m * 16 + kb * 4 + j][wc] = sp[m][j];
  }
  __syncthreads();

  // row scores (128 rows on waves 0-1), two-level max/sum
  const int pi = b * 16 + ch;
  float s = 0.f, pe = 0.f;
  if (tid < 128) {
    s = sc8[tid][0] + sc8[tid][1] + sc8[tid][2] + sc8[tid][3]
      + sc8[tid][4] + sc8[tid][5] + sc8[tid][6] + sc8[tid][7];
    float mx = s;
    #pragma unroll
    for (int off = 1; off < 64; off <<= 1) mx = fmaxf(mx, __shfl_xor(mx, off));
    if (l == 0) red2[w] = mx;
  }
  __syncthreads();
  float Mx = fmaxf(red2[0], red2[1]);
  if (tid < 128) {
    pe = __expf(s - Mx);
    pbuf[tid] = pe;
    float ls = pe;
    #pragma unroll
    for (int off = 1; off < 64; off <<= 1) ls += __shfl_xor(ls, off);
    if (l == 0) red2[4 + w] = ls;
  }
  __syncthreads();
  if (tid == 0) { mpart[pi] = Mx; lpart[pi] = red2[4] + red2[5]; }

  // ctx partial: cv[n] = sum over this wave's 64 rows of p[row]*proj[row][col]
  float cv[4];
  #pragma unroll
  for (int n = 0; n < 4; ++n) cv[n] = 0.f;
  #pragma unroll
  for (int m = 0; m < 4; ++m)
    #pragma unroll
    for (int j = 0; j < 4; ++j) {
      float pw = pbuf[wr * 64 + m * 16 + kb * 4 + j];
      #pragma unroll
      for (int n = 0; n < 4; ++n) cv[n] += pw * acc[m][n][j];
    }
  #pragma unroll
  for (int n = 0; n < 4; ++n) {
    float v = cv[n];
    v += __shfl_xor(v, 16);
    v += __shfl_xor(v, 32);
    cv[n] = v;                         // summed over kb-groups -> all 64 rows
  }
  if (l < 16) {
    #pragma unroll
    for (int n = 0; n < 4; ++n) ctx2[wr][wc * 64 + n * 16 + l] = cv[n];
  }
  __syncthreads();

  if (tid < 512)
    ctxp[(size_t)pi * 512 + tid] = ctx2[0][tid] + ctx2[1][tid];
}

// ---- merge 16 chunk partials per batch (flash-style combine)
__global__ void k_comb(const float* __restrict__ mpart, const float* __restrict__ lpart,
                       const float* __restrict__ ctxp, float* __restrict__ out) {
  int b = blockIdx.x, a = threadIdx.x;
  float Mg = -1e30f;
  #pragma unroll
  for (int i = 0; i < 16; ++i) Mg = fmaxf(Mg, mpart[b * 16 + i]);
  float den = 0.f, s = 0.f;
  #pragma unroll
  for (int i = 0; i < 16; ++i) {
    float e = __expf(mpart[b * 16 + i] - Mg);
    den += lpart[b * 16 + i] * e;
    s   += ctxp[((size_t)(b * 16 + i)) * 512 + a] * e;
  }
  out[(size_t)b * 512 + a] = s / den;
}

extern "C" void kernel_launch(void* const* d_in, const int* in_sizes, int n_in,
                              void* d_out, int out_size, void* d_ws, size_t ws_size,
                              hipStream_t stream) {
  const float* inputs = (const float*)d_in[0];
  const float* query  = (const float*)d_in[1];
  const float* W_in   = (const float*)d_in[2];
  const float* W_q    = (const float*)d_in[3];
  const float* w_att  = (const float*)d_in[4];
  float* out = (float*)d_out;

  char* ws = (char*)d_ws;
  float*    projq = (float*)(ws + WS_PROJQ);
  float*    mpart = (float*)(ws + WS_MPART);
  float*    lpart = (float*)(ws + WS_LPART);
  float*    ctxp  = (float*)(ws + WS_CTXP);
  _Float16* wws   = (_Float16*)(ws + WS_WWS);

  k_prep<<<512, 256, 0, stream>>>(W_in, wws, query, W_q, projq);
  k_main<<<dim3(16, 32), 1024, 0, stream>>>(inputs, wws, projq, w_att, mpart, lpart, ctxp);
  k_comb<<<32, 512, 0, stream>>>(mpart, lpart, ctxp, out);
}